// Round 1
// baseline (206.277 us; speedup 1.0000x reference)
//
#include <hip/hip_runtime.h>
#include <hip/hip_bf16.h>
#include <math.h>

// GPT2 attention: B=8, T=1024, D=768, H=12, hd=64. fp32 in/out, bf16 MFMA compute.
#define B_ 8
#define T_ 1024
#define D_ 768
#define NH 12
#define HD 64

typedef __bf16 bf16x8 __attribute__((ext_vector_type(8)));
typedef float f32x4 __attribute__((ext_vector_type(4)));

// ---------------- x (fp32) -> bf16 ----------------
__global__ void xconv_kernel(const float* __restrict__ x, __bf16* __restrict__ xb, int n8) {
  int i = blockIdx.x * 256 + threadIdx.x;
  if (i >= n8) return;
  const float4* xf = (const float4*)x;
  float4 a = xf[i * 2], b = xf[i * 2 + 1];
  bf16x8 v;
  v[0] = (__bf16)a.x; v[1] = (__bf16)a.y; v[2] = (__bf16)a.z; v[3] = (__bf16)a.w;
  v[4] = (__bf16)b.x; v[5] = (__bf16)b.y; v[6] = (__bf16)b.z; v[7] = (__bf16)b.w;
  *(bf16x8*)&xb[(size_t)i * 8] = v;
}

// ---------------- W (K x N fp32) -> WT (N x K bf16) ----------------
__global__ void wtrans_kernel(const float* __restrict__ W, __bf16* __restrict__ WT, int K, int N) {
  __shared__ float tile[32][33];
  int t = threadIdx.x, col = t & 31, r0 = t >> 5;
  int n0 = blockIdx.x * 32, k0 = blockIdx.y * 32;
#pragma unroll
  for (int p = 0; p < 4; p++) {
    int r = r0 + p * 8;
    tile[r][col] = W[(size_t)(k0 + r) * N + n0 + col];
  }
  __syncthreads();
#pragma unroll
  for (int p = 0; p < 4; p++) {
    int r = r0 + p * 8;
    WT[(size_t)(n0 + r) * K + k0 + col] = (__bf16)tile[col][r];
  }
}

// ---------------- GEMM: C(MxN) = A(MxK) * BT(NxK)^T + bias ----------------
// 128x128 tile, 4 waves (2x2), 64x64 per wave, BK=64, mfma 16x16x32 bf16.
// EPI=0: bf16 output; EPI=1: fp32 output.
template <int EPI>
__global__ __launch_bounds__(256) void gemm_kernel(const __bf16* __restrict__ A,
                                                   const __bf16* __restrict__ BT,
                                                   const float* __restrict__ bias,
                                                   void* __restrict__ Cout,
                                                   int M, int N, int K) {
  __shared__ __align__(16) __bf16 Asm[128][72];  // 144B pitch: conflict-free b128 reads
  __shared__ __align__(16) __bf16 Bsm[128][72];
  int tid = threadIdx.x;
  int wave = tid >> 6, lane = tid & 63, g = lane >> 4, l15 = lane & 15;
  int wr = wave >> 1, wc = wave & 1;
  int m0 = blockIdx.y * 128, n0 = blockIdx.x * 128;
  int srow = tid >> 3, sk8 = tid & 7;
  const __bf16* Ag = A + (size_t)(m0 + srow) * K + sk8 * 8;
  const __bf16* Bg = BT + (size_t)(n0 + srow) * K + sk8 * 8;

  f32x4 zz = {0.0f, 0.0f, 0.0f, 0.0f};
  f32x4 acc[4][4];
#pragma unroll
  for (int m = 0; m < 4; m++)
#pragma unroll
    for (int n = 0; n < 4; n++) acc[m][n] = zz;

  int nk = K >> 6;
  bf16x8 Av[4], Bv[4];
#pragma unroll
  for (int p = 0; p < 4; p++) {
    Av[p] = *(const bf16x8*)(Ag + (size_t)p * 32 * K);
    Bv[p] = *(const bf16x8*)(Bg + (size_t)p * 32 * K);
  }
  for (int kt = 0; kt < nk; kt++) {
    __syncthreads();
#pragma unroll
    for (int p = 0; p < 4; p++) {
      *(bf16x8*)&Asm[srow + p * 32][sk8 * 8] = Av[p];
      *(bf16x8*)&Bsm[srow + p * 32][sk8 * 8] = Bv[p];
    }
    __syncthreads();
    if (kt + 1 < nk) {
#pragma unroll
      for (int p = 0; p < 4; p++) {
        Av[p] = *(const bf16x8*)(Ag + (kt + 1) * 64 + (size_t)p * 32 * K);
        Bv[p] = *(const bf16x8*)(Bg + (kt + 1) * 64 + (size_t)p * 32 * K);
      }
    }
#pragma unroll
    for (int ks = 0; ks < 2; ks++) {
      bf16x8 af[4], bf[4];
#pragma unroll
      for (int m = 0; m < 4; m++) af[m] = *(const bf16x8*)&Asm[wr * 64 + m * 16 + l15][ks * 32 + g * 8];
#pragma unroll
      for (int n = 0; n < 4; n++) bf[n] = *(const bf16x8*)&Bsm[wc * 64 + n * 16 + l15][ks * 32 + g * 8];
#pragma unroll
      for (int m = 0; m < 4; m++)
#pragma unroll
        for (int n = 0; n < 4; n++)
          acc[m][n] = __builtin_amdgcn_mfma_f32_16x16x32_bf16(af[m], bf[n], acc[m][n], 0, 0, 0);
    }
  }
  // epilogue: C/D layout col=lane&15, row=(lane>>4)*4+reg
#pragma unroll
  for (int n = 0; n < 4; n++) {
    int gcol = n0 + wc * 64 + n * 16 + l15;
    float bv = bias[gcol];
#pragma unroll
    for (int m = 0; m < 4; m++) {
      int grow0 = m0 + wr * 64 + m * 16 + g * 4;
#pragma unroll
      for (int r = 0; r < 4; r++) {
        float v = acc[m][n][r] + bv;
        if (EPI == 0)
          ((__bf16*)Cout)[(size_t)(grow0 + r) * N + gcol] = (__bf16)v;
        else
          ((float*)Cout)[(size_t)(grow0 + r) * N + gcol] = v;
      }
    }
  }
}

// ---------------- V from qkv -> VT [bh][d][t] bf16 ----------------
__global__ void vtrepack_kernel(const __bf16* __restrict__ qkv, __bf16* __restrict__ VT) {
  __shared__ __align__(16) __bf16 tl[64][72];  // [d][t] within tile
  int bh = blockIdx.y;
  int b = bh / NH, h = bh % NH;
  int t0 = blockIdx.x * 64;
  int tid = threadIdx.x;
  int tr = tid >> 3, d8 = tid & 7;
#pragma unroll
  for (int p = 0; p < 2; p++) {
    int trow = tr + p * 32;
    bf16x8 v = *(const bf16x8*)&qkv[(size_t)(b * T_ + t0 + trow) * (3 * D_) + 2 * D_ + h * HD + d8 * 8];
#pragma unroll
    for (int e = 0; e < 8; e++) tl[d8 * 8 + e][trow] = v[e];
  }
  __syncthreads();
  int t8 = tid & 7;
#pragma unroll
  for (int p = 0; p < 2; p++) {
    int d = (tid >> 3) + p * 32;
    *(bf16x8*)&VT[((size_t)bh * HD + d) * T_ + t0 + t8 * 8] = *(const bf16x8*)&tl[d][t8 * 8];
  }
}

// ---------------- causal flash attention ----------------
// grid (16 q-tiles, 96 bh); 4 waves x 16 q-rows each; key tiles of 32.
__global__ __launch_bounds__(256) void attn_kernel(const __bf16* __restrict__ qkv,
                                                   const __bf16* __restrict__ VT,
                                                   __bf16* __restrict__ attn_out) {
  __shared__ __align__(16) __bf16 Ksm[32][72];    // [key][d], padded
  __shared__ __align__(16) __bf16 VTsm[64][40];   // [d][key], padded
  __shared__ __align__(16) __bf16 Psm[4][16][40]; // per-wave [q][key], padded
  int qt = blockIdx.x, bh = blockIdx.y;
  int b = bh / NH, h = bh % NH;
  int tid = threadIdx.x;
  int wave = tid >> 6, lane = tid & 63, g = lane >> 4, l15 = lane & 15;
  int q0 = qt * 64 + wave * 16;

  // Q fragments: A-layout row=q=l15, k=d=g*8+e
  const __bf16* qrow = qkv + (size_t)(b * T_ + q0 + l15) * (3 * D_) + h * HD;
  bf16x8 qf0 = *(const bf16x8*)(qrow + g * 8);
  bf16x8 qf1 = *(const bf16x8*)(qrow + 32 + g * 8);

  f32x4 zz = {0.0f, 0.0f, 0.0f, 0.0f};
  f32x4 o[4];
#pragma unroll
  for (int dq = 0; dq < 4; dq++) o[dq] = zz;
  float mrow[4] = {-1e30f, -1e30f, -1e30f, -1e30f};
  float lrow[4] = {0.0f, 0.0f, 0.0f, 0.0f};

  int nkt = qt * 2 + 2;
  int krow = tid >> 3, kd8 = tid & 7;
  int vd = tid >> 2, vk8 = tid & 3;

  for (int kt = 0; kt < nkt; kt++) {
    int key0 = kt * 32;
    __syncthreads();
    *(bf16x8*)&Ksm[krow][kd8 * 8] =
        *(const bf16x8*)&qkv[(size_t)(b * T_ + key0 + krow) * (3 * D_) + D_ + h * HD + kd8 * 8];
    *(bf16x8*)&VTsm[vd][vk8 * 8] =
        *(const bf16x8*)&VT[((size_t)bh * HD + vd) * T_ + key0 + vk8 * 8];
    __syncthreads();

    bf16x8 kf00 = *(const bf16x8*)&Ksm[l15][g * 8];
    bf16x8 kf01 = *(const bf16x8*)&Ksm[l15][32 + g * 8];
    bf16x8 kf10 = *(const bf16x8*)&Ksm[16 + l15][g * 8];
    bf16x8 kf11 = *(const bf16x8*)&Ksm[16 + l15][32 + g * 8];
    f32x4 s0 = __builtin_amdgcn_mfma_f32_16x16x32_bf16(qf0, kf00, zz, 0, 0, 0);
    s0 = __builtin_amdgcn_mfma_f32_16x16x32_bf16(qf1, kf01, s0, 0, 0, 0);
    f32x4 s1 = __builtin_amdgcn_mfma_f32_16x16x32_bf16(qf0, kf10, zz, 0, 0, 0);
    s1 = __builtin_amdgcn_mfma_f32_16x16x32_bf16(qf1, kf11, s1, 0, 0, 0);

    int keyA = key0 + l15, keyB = keyA + 16;
#pragma unroll
    for (int r = 0; r < 4; r++) {
      int qg = q0 + g * 4 + r;
      float a = s0[r] * 0.125f;
      if (keyA > qg) a = -1e30f;
      float c2 = s1[r] * 0.125f;
      if (keyB > qg) c2 = -1e30f;
      float mx = fmaxf(a, c2);
      mx = fmaxf(mx, __shfl_xor(mx, 1));
      mx = fmaxf(mx, __shfl_xor(mx, 2));
      mx = fmaxf(mx, __shfl_xor(mx, 4));
      mx = fmaxf(mx, __shfl_xor(mx, 8));
      float mnew = fmaxf(mrow[r], mx);
      float p0 = __expf(a - mnew), p1 = __expf(c2 - mnew);
      float sum = p0 + p1;
      sum += __shfl_xor(sum, 1);
      sum += __shfl_xor(sum, 2);
      sum += __shfl_xor(sum, 4);
      sum += __shfl_xor(sum, 8);
      float corr = __expf(mrow[r] - mnew);
      lrow[r] = lrow[r] * corr + sum;
      mrow[r] = mnew;
      Psm[wave][g * 4 + r][l15] = (__bf16)p0;
      Psm[wave][g * 4 + r][16 + l15] = (__bf16)p1;
#pragma unroll
      for (int dq = 0; dq < 4; dq++) o[dq][r] *= corr;
    }
    // PV: A = P (row=q=l15, k=key=g*8+e), B = V (col=d, k=key) from VT
    bf16x8 pf = *(const bf16x8*)&Psm[wave][l15][g * 8];
#pragma unroll
    for (int dq = 0; dq < 4; dq++) {
      bf16x8 vf = *(const bf16x8*)&VTsm[dq * 16 + l15][g * 8];
      o[dq] = __builtin_amdgcn_mfma_f32_16x16x32_bf16(pf, vf, o[dq], 0, 0, 0);
    }
  }
#pragma unroll
  for (int r = 0; r < 4; r++) {
    float invl = 1.0f / lrow[r];
    int q = q0 + g * 4 + r;
#pragma unroll
    for (int dq = 0; dq < 4; dq++) {
      attn_out[(size_t)(b * T_ + q) * D_ + h * HD + dq * 16 + l15] = (__bf16)(o[dq][r] * invl);
    }
  }
}

extern "C" void kernel_launch(void* const* d_in, const int* in_sizes, int n_in,
                              void* d_out, int out_size, void* d_ws, size_t ws_size,
                              hipStream_t stream) {
  (void)in_sizes; (void)n_in; (void)out_size; (void)ws_size;
  const float* x = (const float*)d_in[0];
  const float* W_attn = (const float*)d_in[1];
  const float* b_attn = (const float*)d_in[2];
  const float* W_proj = (const float*)d_in[3];
  const float* b_proj = (const float*)d_in[4];

  char* ws = (char*)d_ws;
  __bf16* xb  = (__bf16*)(ws + 0);          // 8192*768*2        = 12,582,912
  __bf16* WaT = (__bf16*)(ws + 12582912);   // 2304*768*2        =  3,538,944
  __bf16* WpT = (__bf16*)(ws + 16121856);   // 768*768*2         =  1,179,648
  __bf16* qkv = (__bf16*)(ws + 17301504);   // 8192*2304*2       = 37,748,736
  __bf16* VTb = (__bf16*)(ws + 55050240);   // 96*64*1024*2      = 12,582,912
  __bf16* att = (__bf16*)(ws + 67633152);   // 8192*768*2        = 12,582,912
  // total 80,216,064 bytes

  xconv_kernel<<<dim3(3072), 256, 0, stream>>>(x, xb, 786432);
  wtrans_kernel<<<dim3(72, 24), 256, 0, stream>>>(W_attn, WaT, 768, 2304);
  wtrans_kernel<<<dim3(24, 24), 256, 0, stream>>>(W_proj, WpT, 768, 768);
  gemm_kernel<0><<<dim3(18, 64), 256, 0, stream>>>(xb, WaT, b_attn, qkv, 8192, 2304, 768);
  vtrepack_kernel<<<dim3(16, 96), 256, 0, stream>>>(qkv, VTb);
  attn_kernel<<<dim3(16, 96), 256, 0, stream>>>(qkv, VTb, att);
  gemm_kernel<1><<<dim3(6, 64), 256, 0, stream>>>(att, WpT, b_proj, d_out, 8192, 768, 768);
}

// Round 2
// 146.727 us; speedup vs baseline: 1.4059x; 1.4059x over previous
//
#include <hip/hip_runtime.h>
#include <hip/hip_bf16.h>
#include <math.h>

// GPT2 attention: B=8, T=1024, D=768, H=12, hd=64. fp32 in/out, bf16 MFMA compute.
#define B_ 8
#define T_ 1024
#define D_ 768
#define NH 12
#define HD 64

typedef __bf16 bf16x8 __attribute__((ext_vector_type(8)));
typedef __bf16 bf16x4 __attribute__((ext_vector_type(4)));
typedef float f32x4 __attribute__((ext_vector_type(4)));

// ---------------- x (fp32) -> bf16 ----------------
__global__ void xconv_kernel(const float* __restrict__ x, __bf16* __restrict__ xb, int n8) {
  int i = blockIdx.x * 256 + threadIdx.x;
  if (i >= n8) return;
  const float4* xf = (const float4*)x;
  float4 a = xf[i * 2], b = xf[i * 2 + 1];
  bf16x8 v;
  v[0] = (__bf16)a.x; v[1] = (__bf16)a.y; v[2] = (__bf16)a.z; v[3] = (__bf16)a.w;
  v[4] = (__bf16)b.x; v[5] = (__bf16)b.y; v[6] = (__bf16)b.z; v[7] = (__bf16)b.w;
  *(bf16x8*)&xb[(size_t)i * 8] = v;
}

// ---------------- W (K x N fp32) -> WT (N x K bf16) ----------------
__global__ void wtrans_kernel(const float* __restrict__ W, __bf16* __restrict__ WT, int K, int N) {
  __shared__ float tile[32][33];
  int t = threadIdx.x, col = t & 31, r0 = t >> 5;
  int n0 = blockIdx.x * 32, k0 = blockIdx.y * 32;
#pragma unroll
  for (int p = 0; p < 4; p++) {
    int r = r0 + p * 8;
    tile[r][col] = W[(size_t)(k0 + r) * N + n0 + col];
  }
  __syncthreads();
#pragma unroll
  for (int p = 0; p < 4; p++) {
    int r = r0 + p * 8;
    WT[(size_t)(n0 + r) * K + k0 + col] = (__bf16)tile[col][r];
  }
}

// ---------------- GEMM: C(MxN) = A(MxK) * BT(NxK)^T + bias ----------------
template <int EPI>
__global__ __launch_bounds__(256) void gemm_kernel(const __bf16* __restrict__ A,
                                                   const __bf16* __restrict__ BT,
                                                   const float* __restrict__ bias,
                                                   void* __restrict__ Cout,
                                                   int M, int N, int K) {
  __shared__ __align__(16) __bf16 Asm[128][72];
  __shared__ __align__(16) __bf16 Bsm[128][72];
  int tid = threadIdx.x;
  int wave = tid >> 6, lane = tid & 63, g = lane >> 4, l15 = lane & 15;
  int wr = wave >> 1, wc = wave & 1;
  int m0 = blockIdx.y * 128, n0 = blockIdx.x * 128;
  int srow = tid >> 3, sk8 = tid & 7;
  const __bf16* Ag = A + (size_t)(m0 + srow) * K + sk8 * 8;
  const __bf16* Bg = BT + (size_t)(n0 + srow) * K + sk8 * 8;

  f32x4 zz = {0.0f, 0.0f, 0.0f, 0.0f};
  f32x4 acc[4][4];
#pragma unroll
  for (int m = 0; m < 4; m++)
#pragma unroll
    for (int n = 0; n < 4; n++) acc[m][n] = zz;

  int nk = K >> 6;
  bf16x8 Av[4], Bv[4];
#pragma unroll
  for (int p = 0; p < 4; p++) {
    Av[p] = *(const bf16x8*)(Ag + (size_t)p * 32 * K);
    Bv[p] = *(const bf16x8*)(Bg + (size_t)p * 32 * K);
  }
  for (int kt = 0; kt < nk; kt++) {
    __syncthreads();
#pragma unroll
    for (int p = 0; p < 4; p++) {
      *(bf16x8*)&Asm[srow + p * 32][sk8 * 8] = Av[p];
      *(bf16x8*)&Bsm[srow + p * 32][sk8 * 8] = Bv[p];
    }
    __syncthreads();
    if (kt + 1 < nk) {
#pragma unroll
      for (int p = 0; p < 4; p++) {
        Av[p] = *(const bf16x8*)(Ag + (kt + 1) * 64 + (size_t)p * 32 * K);
        Bv[p] = *(const bf16x8*)(Bg + (kt + 1) * 64 + (size_t)p * 32 * K);
      }
    }
#pragma unroll
    for (int ks = 0; ks < 2; ks++) {
      bf16x8 af[4], bfr[4];
#pragma unroll
      for (int m = 0; m < 4; m++) af[m] = *(const bf16x8*)&Asm[wr * 64 + m * 16 + l15][ks * 32 + g * 8];
#pragma unroll
      for (int n = 0; n < 4; n++) bfr[n] = *(const bf16x8*)&Bsm[wc * 64 + n * 16 + l15][ks * 32 + g * 8];
#pragma unroll
      for (int m = 0; m < 4; m++)
#pragma unroll
        for (int n = 0; n < 4; n++)
          acc[m][n] = __builtin_amdgcn_mfma_f32_16x16x32_bf16(af[m], bfr[n], acc[m][n], 0, 0, 0);
    }
  }
#pragma unroll
  for (int n = 0; n < 4; n++) {
    int gcol = n0 + wc * 64 + n * 16 + l15;
    float bv = bias[gcol];
#pragma unroll
    for (int m = 0; m < 4; m++) {
      int grow0 = m0 + wr * 64 + m * 16 + g * 4;
#pragma unroll
      for (int r = 0; r < 4; r++) {
        float v = acc[m][n][r] + bv;
        if (EPI == 0)
          ((__bf16*)Cout)[(size_t)(grow0 + r) * N + gcol] = (__bf16)v;
        else
          ((float*)Cout)[(size_t)(grow0 + r) * N + gcol] = v;
      }
    }
  }
}

// ---------------- V from qkv -> VT [bh][d][t] bf16 ----------------
__global__ void vtrepack_kernel(const __bf16* __restrict__ qkv, __bf16* __restrict__ VT) {
  __shared__ __align__(16) __bf16 tl[64][72];
  int bh = blockIdx.y;
  int b = bh / NH, h = bh % NH;
  int t0 = blockIdx.x * 64;
  int tid = threadIdx.x;
  int tr = tid >> 3, d8 = tid & 7;
#pragma unroll
  for (int p = 0; p < 2; p++) {
    int trow = tr + p * 32;
    bf16x8 v = *(const bf16x8*)&qkv[(size_t)(b * T_ + t0 + trow) * (3 * D_) + 2 * D_ + h * HD + d8 * 8];
#pragma unroll
    for (int e = 0; e < 8; e++) tl[d8 * 8 + e][trow] = v[e];
  }
  __syncthreads();
  int t8 = tid & 7;
#pragma unroll
  for (int p = 0; p < 2; p++) {
    int d = (tid >> 3) + p * 32;
    *(bf16x8*)&VT[((size_t)bh * HD + d) * T_ + t0 + t8 * 8] = *(const bf16x8*)&tl[d][t8 * 8];
  }
}

// ---------------- causal flash attention, wave-independent, swapped QK^T ----------------
// grid (24 bh-groups, 32 q-tiles); 4 independent waves/block, each wave = one bh,
// 32 q-rows (two 16-row mfma tiles sharing K frags), KVBLK=32, zero __syncthreads.
// S^T = mfma(A=K, B=Q): lane(g,l15) holds S[key0+{g*4+r}][q0+l15] -> row softmax is
// lane-local over 8 vals + shfl_xor(16,32). P transposed to PV B-frag via tiny
// per-wave LDS. O^T = mfma(A=V^T, B=P^T).
__device__ __forceinline__ void softmax_update(const f32x4& sA, const f32x4& sB, int maskmode,
                                               int l15, int g, float& m, float& l,
                                               f32x4* o, __bf16* prow) {
  float v[8];
#pragma unroll
  for (int r = 0; r < 4; r++) { v[r] = sA[r] * 0.125f; v[4 + r] = sB[r] * 0.125f; }
  if (maskmode == 1) {
#pragma unroll
    for (int r = 0; r < 4; r++) { if (g * 4 + r > l15) v[r] = -1e30f; v[4 + r] = -1e30f; }
  } else if (maskmode == 2) {
#pragma unroll
    for (int r = 0; r < 4; r++) { if (g * 4 + r > l15) v[4 + r] = -1e30f; }
  }
  float mx = v[0];
#pragma unroll
  for (int i = 1; i < 8; i++) mx = fmaxf(mx, v[i]);
  mx = fmaxf(mx, __shfl_xor(mx, 16));
  mx = fmaxf(mx, __shfl_xor(mx, 32));
  float mnew = fmaxf(m, mx);
  float corr = __expf(m - mnew);
  float p[8], sum = 0.0f;
#pragma unroll
  for (int i = 0; i < 8; i++) { p[i] = __expf(v[i] - mnew); sum += p[i]; }
  sum += __shfl_xor(sum, 16);
  sum += __shfl_xor(sum, 32);
  l = l * corr + sum;
  m = mnew;
#pragma unroll
  for (int dq = 0; dq < 4; dq++) o[dq] *= corr;
  bf16x4 wa = {(__bf16)p[0], (__bf16)p[1], (__bf16)p[2], (__bf16)p[3]};
  bf16x4 wb = {(__bf16)p[4], (__bf16)p[5], (__bf16)p[6], (__bf16)p[7]};
  *(bf16x4*)&prow[g * 4] = wa;
  *(bf16x4*)&prow[16 + g * 4] = wb;
}

__global__ __launch_bounds__(256) void attn_kernel(const __bf16* __restrict__ qkv,
                                                   const __bf16* __restrict__ VT,
                                                   __bf16* __restrict__ attn_out) {
  __shared__ __align__(16) __bf16 Psm[4][2][16][40];  // [wave][qtile][q][key], 80B pitch
  int tid = threadIdx.x;
  int wave = tid >> 6, lane = tid & 63, g = lane >> 4, l15 = lane & 15;
  int qw = 31 - blockIdx.y;            // heavy q-tiles dispatched first
  int bh = blockIdx.x * 4 + wave;
  int b = bh / NH, h = bh % NH;
  int q0 = qw * 32;

  // Q fragments (B-operand: col=q=l15, k=d=g*8+e), two q-tiles
  const __bf16* Qa = qkv + (size_t)(b * T_ + q0 + l15) * (3 * D_) + h * HD;
  const __bf16* Qb = Qa + (size_t)16 * (3 * D_);
  bf16x8 qa0 = *(const bf16x8*)(Qa + g * 8);
  bf16x8 qa1 = *(const bf16x8*)(Qa + 32 + g * 8);
  bf16x8 qb0 = *(const bf16x8*)(Qb + g * 8);
  bf16x8 qb1 = *(const bf16x8*)(Qb + 32 + g * 8);

  f32x4 zz = {0.0f, 0.0f, 0.0f, 0.0f};
  f32x4 o_a[4], o_b[4];
#pragma unroll
  for (int dq = 0; dq < 4; dq++) { o_a[dq] = zz; o_b[dq] = zz; }
  float m_a = -1e30f, l_a = 0.0f, m_b = -1e30f, l_b = 0.0f;

  __bf16* prowA = &Psm[wave][0][l15][0];
  __bf16* prowB = &Psm[wave][1][l15][0];
  const __bf16* Kbase = qkv + (size_t)(b * T_) * (3 * D_) + D_ + h * HD;
  const __bf16* Vbase = VT + ((size_t)bh * HD + l15) * T_;

  for (int kt = 0; kt <= qw; kt++) {
    int key0 = kt * 32;
    const __bf16* Kb = Kbase + (size_t)key0 * (3 * D_);
    bf16x8 kf0 = *(const bf16x8*)(Kb + (size_t)l15 * (3 * D_) + g * 8);
    bf16x8 kf1 = *(const bf16x8*)(Kb + (size_t)l15 * (3 * D_) + 32 + g * 8);
    bf16x8 kg0 = *(const bf16x8*)(Kb + (size_t)(16 + l15) * (3 * D_) + g * 8);
    bf16x8 kg1 = *(const bf16x8*)(Kb + (size_t)(16 + l15) * (3 * D_) + 32 + g * 8);
    const __bf16* Vb = Vbase + key0 + g * 8;
    bf16x8 vf0 = *(const bf16x8*)(Vb);
    bf16x8 vf1 = *(const bf16x8*)(Vb + 16 * T_);
    bf16x8 vf2 = *(const bf16x8*)(Vb + 32 * T_);
    bf16x8 vf3 = *(const bf16x8*)(Vb + 48 * T_);

    f32x4 sAa = __builtin_amdgcn_mfma_f32_16x16x32_bf16(kf0, qa0, zz, 0, 0, 0);
    sAa = __builtin_amdgcn_mfma_f32_16x16x32_bf16(kf1, qa1, sAa, 0, 0, 0);
    f32x4 sBa = __builtin_amdgcn_mfma_f32_16x16x32_bf16(kg0, qa0, zz, 0, 0, 0);
    sBa = __builtin_amdgcn_mfma_f32_16x16x32_bf16(kg1, qa1, sBa, 0, 0, 0);
    f32x4 sAb = __builtin_amdgcn_mfma_f32_16x16x32_bf16(kf0, qb0, zz, 0, 0, 0);
    sAb = __builtin_amdgcn_mfma_f32_16x16x32_bf16(kf1, qb1, sAb, 0, 0, 0);
    f32x4 sBb = __builtin_amdgcn_mfma_f32_16x16x32_bf16(kg0, qb0, zz, 0, 0, 0);
    sBb = __builtin_amdgcn_mfma_f32_16x16x32_bf16(kg1, qb1, sBb, 0, 0, 0);

    int last = (kt == qw);
    softmax_update(sAa, sBa, last ? 1 : 0, l15, g, m_a, l_a, o_a, prowA);
    softmax_update(sAb, sBb, last ? 2 : 0, l15, g, m_b, l_b, o_b, prowB);

    bf16x8 pa = *(const bf16x8*)&Psm[wave][0][l15][g * 8];
    bf16x8 pb = *(const bf16x8*)&Psm[wave][1][l15][g * 8];
#pragma unroll
    for (int dq = 0; dq < 4; dq++) {
      bf16x8 vf = (dq == 0) ? vf0 : (dq == 1) ? vf1 : (dq == 2) ? vf2 : vf3;
      o_a[dq] = __builtin_amdgcn_mfma_f32_16x16x32_bf16(vf, pa, o_a[dq], 0, 0, 0);
      o_b[dq] = __builtin_amdgcn_mfma_f32_16x16x32_bf16(vf, pb, o_b[dq], 0, 0, 0);
    }
  }

  float invla = 1.0f / l_a, invlb = 1.0f / l_b;
  __bf16* outA = attn_out + (size_t)(b * T_ + q0 + l15) * D_ + h * HD;
  __bf16* outB = outA + (size_t)16 * D_;
#pragma unroll
  for (int dq = 0; dq < 4; dq++) {
#pragma unroll
    for (int r = 0; r < 4; r++) {
      int d = dq * 16 + g * 4 + r;
      outA[d] = (__bf16)(o_a[dq][r] * invla);
      outB[d] = (__bf16)(o_b[dq][r] * invlb);
    }
  }
}

extern "C" void kernel_launch(void* const* d_in, const int* in_sizes, int n_in,
                              void* d_out, int out_size, void* d_ws, size_t ws_size,
                              hipStream_t stream) {
  (void)in_sizes; (void)n_in; (void)out_size; (void)ws_size;
  const float* x = (const float*)d_in[0];
  const float* W_attn = (const float*)d_in[1];
  const float* b_attn = (const float*)d_in[2];
  const float* W_proj = (const float*)d_in[3];
  const float* b_proj = (const float*)d_in[4];

  char* ws = (char*)d_ws;
  __bf16* xb  = (__bf16*)(ws + 0);          // 8192*768*2        = 12,582,912
  __bf16* WaT = (__bf16*)(ws + 12582912);   // 2304*768*2        =  3,538,944
  __bf16* WpT = (__bf16*)(ws + 16121856);   // 768*768*2         =  1,179,648
  __bf16* qkv = (__bf16*)(ws + 17301504);   // 8192*2304*2       = 37,748,736
  __bf16* VTb = (__bf16*)(ws + 55050240);   // 96*64*1024*2      = 12,582,912
  __bf16* att = (__bf16*)(ws + 67633152);   // 8192*768*2        = 12,582,912

  xconv_kernel<<<dim3(3072), 256, 0, stream>>>(x, xb, 786432);
  wtrans_kernel<<<dim3(72, 24), 256, 0, stream>>>(W_attn, WaT, 768, 2304);
  wtrans_kernel<<<dim3(24, 24), 256, 0, stream>>>(W_proj, WpT, 768, 768);
  gemm_kernel<0><<<dim3(18, 64), 256, 0, stream>>>(xb, WaT, b_attn, qkv, 8192, 2304, 768);
  vtrepack_kernel<<<dim3(16, 96), 256, 0, stream>>>(qkv, VTb);
  attn_kernel<<<dim3(24, 32), 256, 0, stream>>>(qkv, VTb, att);
  gemm_kernel<1><<<dim3(6, 64), 256, 0, stream>>>(att, WpT, b_proj, d_out, 8192, 768, 768);
}